// Round 28
// baseline (181.300 us; speedup 1.0000x reference)
//
#include <hip/hip_runtime.h>
#include <math.h>

#define NTOK 65536
#define DIMD 128
#define KCB  2048
#define TSLAB 256   // tail histogram slabs

typedef unsigned short u16;
typedef __attribute__((ext_vector_type(8))) unsigned short u16x8;
typedef __attribute__((ext_vector_type(8))) __bf16 bf16x8;
typedef __attribute__((ext_vector_type(4))) float f32x4;

union U8 { u16x8 u; bf16x8 b; };

__device__ __forceinline__ u16 f2bf(float f) {
  union { float f; unsigned u; } c; c.f = f;
  unsigned r = c.u + 0x7FFFu + ((c.u >> 16) & 1u);
  return (u16)(r >> 16);
}
__device__ __forceinline__ float keyval(int k) {
  union { int i; float f; } c; c.i = k & 0xFFFFF800;
  return c.f;
}
__device__ __forceinline__ int imax(int a, int b) { return a > b ? a : b; }
__device__ __forceinline__ int imin(int a, int b) { return a < b ? a : b; }

// linear tile staging (16KB) with 256 threads: thread tid covers bytes [tid*16 + i*4096]
__device__ __forceinline__ void stage4(const char* srcLane, char* ldsWaveBase) {
  #pragma unroll
  for (int i = 0; i < 4; ++i)
    __builtin_amdgcn_global_load_lds((const __attribute__((address_space(1))) void*)(srcLane + i * 4096),
                                     (__attribute__((address_space(3))) void*)(ldsWaveBase + i * 4096), 16, 0, 0);
}

// ---------------- small kernels ----------------

// pack codebook to plain bf16 in MFMA-fragment order, 64-code tiles, H only; gid 0 zeroes acc
__global__ __launch_bounds__(256) void k_packcb(const float* __restrict__ cb, u16* __restrict__ cbp,
                                                float* __restrict__ acc4) {
  const int gid = blockIdx.x * 256 + threadIdx.x;
  if (gid == 0) { acc4[0] = 0.0f; acc4[1] = 0.0f; acc4[2] = 0.0f; acc4[3] = 0.0f; }
  if (gid >= 32768) return;
  const int lane = gid & 63;
  const int f = (gid >> 6) & 15;
  const int T = gid >> 10;
  const int ks = f >> 2, nf = f & 3;
  const int hi = lane >> 4, l15 = lane & 15;
  const int c = T * 64 + nf * 16 + l15;
  const int d0 = ks * 32 + hi * 8;
  const float4 v0 = *(const float4*)(cb + (size_t)c * DIMD + d0);
  const float4 v1 = *(const float4*)(cb + (size_t)c * DIMD + d0 + 4);
  const float e[8] = {v0.x, v0.y, v0.z, v0.w, v1.x, v1.y, v1.z, v1.w};
  union { u16 s[8]; u16x8 u; } oh;
  #pragma unroll
  for (int i = 0; i < 8; ++i) oh.s[i] = f2bf(e[i]);
  u16* tile = cbp + (size_t)T * 8192;
  *(u16x8*)(tile + (f * 64 + lane) * 8) = oh.u;
}

// ---------------- sweep: bf16 MFMA over HALF the codebook per block; per-lane int top-2 ----------------
// grid = 1024: blockIdx = rowgrp*2 + half. 4 waves x 32 rows (m=2). 4 blocks/CU.

__global__ __launch_bounds__(256, 4) void k_sweep(const float* __restrict__ x, const float* __restrict__ mask,
                                                  const u16* __restrict__ cbp, int* __restrict__ kvBuf) {
  __shared__ __align__(16) char Bsmem[32768];  // 2 x 16KB tiles
  const int tid = threadIdx.x;
  const int lane = tid & 63, w = tid >> 6;     // 4 waves
  const int l15 = lane & 15, hi = lane >> 4;
  const int half = blockIdx.x & 1;
  const int row0 = (blockIdx.x >> 1) * 128;
  const char* src = (const char*)cbp + (size_t)half * 262144;  // 16 tiles x 16KB

  // fused prep: load x f32, row-norm via 2-step shuffle (4 lanes/row), to plain bf16 in regs
  U8 Ah[2][4];
  #pragma unroll
  for (int mf = 0; mf < 2; ++mf) {
    const int row = row0 + w * 32 + mf * 16 + l15;
    const float add = (1.0f - mask[row]) * 1e-6f;
    const float* xr = x + (size_t)row * DIMD + hi * 8;
    float xf[4][8];
    float ss = 0.f;
    #pragma unroll
    for (int ks = 0; ks < 4; ++ks) {
      const float4 a = *(const float4*)(xr + ks * 32);
      const float4 bq = *(const float4*)(xr + ks * 32 + 4);
      xf[ks][0] = a.x + add;  xf[ks][1] = a.y + add;  xf[ks][2] = a.z + add;  xf[ks][3] = a.w + add;
      xf[ks][4] = bq.x + add; xf[ks][5] = bq.y + add; xf[ks][6] = bq.z + add; xf[ks][7] = bq.w + add;
      #pragma unroll
      for (int e = 0; e < 8; ++e) ss = fmaf(xf[ks][e], xf[ks][e], ss);
    }
    ss += __shfl_xor(ss, 16, 64);
    ss += __shfl_xor(ss, 32, 64);
    const float sc = 1.0f / fmaxf(sqrtf(ss), 1e-6f);
    #pragma unroll
    for (int ks = 0; ks < 4; ++ks) {
      union { u16 s[8]; u16x8 u; } th;
      #pragma unroll
      for (int e = 0; e < 8; ++e) th.s[e] = f2bf(xf[ks][e] * sc);
      Ah[mf][ks].u = th.u;
    }
  }

  // index-packed top-2 keys: key = (asint(score) & ~2047) | code_index
  int kv1[8], kv2[8];
  #pragma unroll
  for (int r = 0; r < 8; ++r) { kv1[r] = 0x80000000; kv2[r] = 0x80000000; }

  stage4(src + 0 * 16384 + tid * 16, Bsmem + 0 * 16384 + w * 1024);

  for (int t = 0; t < 16; ++t) {
    const int b = t & 1;
    asm volatile("s_waitcnt vmcnt(0)" ::: "memory");
    __builtin_amdgcn_sched_barrier(0);
    __builtin_amdgcn_s_barrier();
    __builtin_amdgcn_sched_barrier(0);
    if (t < 15)
      stage4(src + (size_t)(t + 1) * 16384 + tid * 16, Bsmem + (b ^ 1) * 16384 + w * 1024);

    const char* base = Bsmem + b * 16384 + lane * 16;
    f32x4 acc[2][4];
    #pragma unroll
    for (int m = 0; m < 2; ++m)
      #pragma unroll
      for (int nf = 0; nf < 4; ++nf) acc[m][nf] = (f32x4){0.f, 0.f, 0.f, 0.f};

    __builtin_amdgcn_s_setprio(1);
    #pragma unroll
    for (int ks = 0; ks < 4; ++ks) {
      #pragma unroll
      for (int nf = 0; nf < 4; ++nf) {
        U8 bh;
        bh.u = *(const u16x8*)(base + ((ks * 4 + nf) << 10));
        acc[0][nf] = __builtin_amdgcn_mfma_f32_16x16x32_bf16(Ah[0][ks].b, bh.b, acc[0][nf], 0, 0, 0);
        acc[1][nf] = __builtin_amdgcn_mfma_f32_16x16x32_bf16(Ah[1][ks].b, bh.b, acc[1][nf], 0, 0, 0);
      }
    }
    __builtin_amdgcn_s_setprio(0);

    // epilogue: index-packed int top-2 (pure max/min tree; overlaps in-flight prefetch)
    const int base11 = half * 1024 + t * 64 + l15;
    #pragma unroll
    for (int m = 0; m < 2; ++m)
      #pragma unroll
      for (int rg = 0; rg < 4; ++rg) {
        const int r = m * 4 + rg;
        int kk[4];
        #pragma unroll
        for (int nf = 0; nf < 4; ++nf) {
          union { float f; int i; } cv;
          cv.f = acc[m][nf][rg];
          kk[nf] = (cv.i & 0xFFFFF800) | (base11 + nf * 16);
        }
        const int h1 = imax(kk[0], kk[1]), lo1 = imin(kk[0], kk[1]);
        const int h2 = imax(kk[2], kk[3]), lo2 = imin(kk[2], kk[3]);
        const int t1 = imax(h1, h2);
        const int t2 = imax(imin(h1, h2), (h1 > h2) ? lo1 : lo2);
        kv2[r] = imax(imax(kv2[r], t2), imin(kv1[r], t1));
        kv1[r] = imax(kv1[r], t1);
      }
  }

  // write per-lane top-2 keys: kvBuf[row*64 + half*32 + l15*2 + {0,1}]
  #pragma unroll
  for (int m = 0; m < 2; ++m)
    #pragma unroll
    for (int rg = 0; rg < 4; ++rg) {
      const int r = m * 4 + rg;
      const int row = row0 + w * 32 + m * 16 + hi * 4 + rg;
      int2 kv;
      kv.x = kv1[r];
      kv.y = kv2[r];
      *(int2*)(kvBuf + (size_t)row * 64 + half * 32 + l15 * 2) = kv;
    }
}

// ---------------- tail: merge 64 keys/row, exact refine, gather, histograms, stats ----------------
// 256 blocks x 4 waves; one wave per row per iteration.

__global__ __launch_bounds__(256) void k_tail(const float* __restrict__ x, const float* __restrict__ mask,
                                              const float* __restrict__ cb, const int* __restrict__ kvBuf,
                                              float* __restrict__ outQ, float* __restrict__ outEnc,
                                              float* __restrict__ apPart, float* __restrict__ cnPart,
                                              float* __restrict__ acc4) {
  __shared__ float ap[KCB];
  __shared__ float cn[KCB];
  __shared__ float smr[12];
  const int tid = threadIdx.x;
  const int lane = tid & 63, w = tid >> 6;
  for (int i = tid; i < KCB; i += 256) { ap[i] = 0.0f; cn[i] = 0.0f; }
  __syncthreads();

  float msum = 0.f, slat = 0.f, sent = 0.f;
  for (int row = blockIdx.x * 4 + w; row < NTOK; row += TSLAB * 4) {
    const int key = kvBuf[(size_t)row * 64 + lane];
    // row max over the 64 keys (int compare == float compare for the positive max)
    int mx = key;
    #pragma unroll
    for (int off = 1; off <= 32; off <<= 1) {
      const int ok = __shfl_xor(mx, off, 64);
      mx = ok > mx ? ok : mx;
    }
    const float a1val = keyval(mx);
    const float myval = keyval(key);
    const float mkk = mask[row];
    const float add = (1.0f - mkk) * 1e-6f;
    // normalized x: 2 dims per lane
    const float2 xv = *(const float2*)(x + (size_t)row * DIMD + lane * 2);
    const float x0 = xv.x + add, x1 = xv.y + add;
    float ss = fmaf(x0, x0, x1 * x1);
    #pragma unroll
    for (int off = 1; off <= 32; off <<= 1) ss += __shfl_xor(ss, off, 64);
    const float sc = 1.0f / fmaxf(sqrtf(ss), 1e-6f);
    // exact re-score of all candidates within RT of the bf16 max
    unsigned long long cmask = __ballot(myval > a1val - 4e-3f);
    float bestd = -1e30f;
    int bestk = 0x7fffffff;
    while (cmask) {
      const int s = __builtin_ctzll(cmask);
      cmask &= cmask - 1;
      const int kc = __shfl(key, s, 64) & 2047;
      const float2 cv = *(const float2*)(cb + (size_t)kc * DIMD + lane * 2);
      float d = fmaf(x0, cv.x, x1 * cv.y);
      #pragma unroll
      for (int off = 1; off <= 32; off <<= 1) d += __shfl_xor(d, off, 64);
      if (d > bestd || (d == bestd && kc < bestk)) { bestd = d; bestk = kc; }
    }
    const float bestv = bestd * sc;
    // histogram weights over all 64 keys (loose-threshold outputs)
    float q = 0.f, qd = 0.f;
    if (myval > a1val - 0.055f) {
      const float d = 200.f * (myval - a1val);
      q = __expf(d);
      qd = q * d;
    }
    float Z = q, S = qd;
    #pragma unroll
    for (int off = 1; off <= 32; off <<= 1) {
      Z += __shfl_xor(Z, off, 64);
      S += __shfl_xor(S, off, 64);
    }
    if (q > 0.f) atomicAdd(&ap[key & 2047], mkk * q / Z);
    // gather the exact-argmax codebook row (2 floats per lane)
    const float2 g = *(const float2*)(cb + (size_t)bestk * DIMD + lane * 2);
    *(float2*)(outQ + (size_t)row * DIMD + lane * 2) = g;
    if (lane == 0) {
      atomicAdd(&cn[bestk], mkk);
      outEnc[row] = (float)bestk;
      msum += mkk;
      slat = fmaf(mkk, 2.0f - 2.0f * bestv, slat);
      sent = fmaf(mkk, __logf(Z) - S / Z, sent);
    }
  }
  // block-reduce the three scalars (only lane 0 holds nonzero)
  #pragma unroll
  for (int off = 1; off <= 32; off <<= 1) {
    msum += __shfl_xor(msum, off, 64);
    slat += __shfl_xor(slat, off, 64);
    sent += __shfl_xor(sent, off, 64);
  }
  if (lane == 0) { smr[w * 3] = msum; smr[w * 3 + 1] = slat; smr[w * 3 + 2] = sent; }
  __syncthreads();
  if (tid == 0) {
    float t0 = 0.f, t1 = 0.f, t2 = 0.f;
    #pragma unroll
    for (int v = 0; v < 4; ++v) { t0 += smr[v * 3]; t1 += smr[v * 3 + 1]; t2 += smr[v * 3 + 2]; }
    atomicAdd(&acc4[0], t0);
    atomicAdd(&acc4[1], t1);
    atomicAdd(&acc4[2], t2);
  }
  float* apDst = apPart + (size_t)blockIdx.x * KCB;
  float* cnDst = cnPart + (size_t)blockIdx.x * KCB;
  for (int i = tid; i < KCB; i += 256) {
    apDst[i] = ap[i];
    cnDst[i] = cn[i];
  }
}

// reduce partial slabs -> avgp-entropy partials + outCnt. 64 blocks x 256 threads, coalesced.
__global__ __launch_bounds__(256) void k_reduce(const float* __restrict__ apPart, const float* __restrict__ cnPart,
                                                const float* __restrict__ acc4In, float* __restrict__ outCnt,
                                                float* __restrict__ acc4) {
  __shared__ float sa8[8][32];
  __shared__ float sc8[8][32];
  const int tid = threadIdx.x;
  const int kloc = tid & 31, sg = tid >> 5;
  const int k = blockIdx.x * 32 + kloc;
  float sa = 0.f, sc = 0.f;
  #pragma unroll
  for (int i = 0; i < 32; ++i) {
    const int s = sg * 32 + i;
    sa += apPart[(size_t)s * KCB + k];
    sc += cnPart[(size_t)s * KCB + k];
  }
  sa8[sg][kloc] = sa;
  sc8[sg][kloc] = sc;
  __syncthreads();
  if (tid < 32) {
    float ta = 0.f, tc = 0.f;
    #pragma unroll
    for (int g = 0; g < 8; ++g) { ta += sa8[g][tid]; tc += sc8[g][tid]; }
    outCnt[blockIdx.x * 32 + tid] = tc;
    const float a = ta / acc4In[0];
    float ae = a * __logf(a + 1e-5f);
    #pragma unroll
    for (int off = 1; off <= 16; off <<= 1) ae += __shfl_xor(ae, off, 64);
    if (tid == 0) atomicAdd(&acc4[3], ae);
  }
}

__global__ __launch_bounds__(64) void k_final(const float* __restrict__ acc4, float* __restrict__ out3) {
  if (threadIdx.x == 0) {
    const float msum = acc4[0];
    const float lat = acc4[1] / (msum + 1e-6f);
    out3[0] = lat;
    out3[1] = lat;
    out3[2] = acc4[2] / msum + acc4[3];  // sample_entropy - avg_entropy
  }
}

// ---------------- launcher ----------------

extern "C" void kernel_launch(void* const* d_in, const int* in_sizes, int n_in,
                              void* d_out, int out_size, void* d_ws, size_t ws_size,
                              hipStream_t stream) {
  const float* x = (const float*)d_in[0];
  const float* mask = (const float*)d_in[1];
  const float* cb = (const float*)d_in[2];

  float* out = (float*)d_out;
  float* outQ = out;
  float* out3 = out + (size_t)NTOK * DIMD;
  float* outCnt = out3 + 3;
  float* outEnc = outCnt + KCB;

  float* ws = (float*)d_ws;
  float* acc4 = ws;                                       // 4
  u16* cbp = (u16*)(acc4 + 8);                            // K*D u16 (512 KB, H only)
  int* kvBuf = (int*)(cbp + (size_t)KCB * DIMD);          // N*64 ints (16 MB)
  float* apPart = (float*)(kvBuf + (size_t)NTOK * 64);    // TSLAB*K (2 MB)
  float* cnPart = apPart + (size_t)TSLAB * KCB;           // TSLAB*K (2 MB)

  k_packcb<<<32768 / 256, 256, 0, stream>>>(cb, cbp, acc4);
  k_sweep<<<(NTOK / 128) * 2, 256, 0, stream>>>(x, mask, cbp, kvBuf);
  k_tail<<<TSLAB, 256, 0, stream>>>(x, mask, cb, kvBuf, outQ, outEnc, apPart, cnPart, acc4);
  k_reduce<<<64, 256, 0, stream>>>(apPart, cnPart, acc4, outCnt, acc4);
  k_final<<<1, 64, 0, stream>>>(acc4, out3);
}

// Round 29
// 111.814 us; speedup vs baseline: 1.6214x; 1.6214x over previous
//
#include <hip/hip_runtime.h>
#include <math.h>

#define NTOK 65536
#define DIMD 128
#define KCB  2048
#define TSLAB 256   // tail histogram slabs

typedef unsigned short u16;
typedef __attribute__((ext_vector_type(8))) unsigned short u16x8;
typedef __attribute__((ext_vector_type(8))) __bf16 bf16x8;
typedef __attribute__((ext_vector_type(4))) float f32x4;

union U8 { u16x8 u; bf16x8 b; };

__device__ __forceinline__ u16 f2bf(float f) {
  union { float f; unsigned u; } c; c.f = f;
  unsigned r = c.u + 0x7FFFu + ((c.u >> 16) & 1u);
  return (u16)(r >> 16);
}
__device__ __forceinline__ float keyval(int k) {
  union { int i; float f; } c; c.i = k & 0xFFFFF800;
  return c.f;
}
__device__ __forceinline__ int imax(int a, int b) { return a > b ? a : b; }
__device__ __forceinline__ int imin(int a, int b) { return a < b ? a : b; }

// linear tile staging (16KB) with 256 threads: thread tid covers bytes [tid*16 + i*4096]
__device__ __forceinline__ void stage4(const char* srcLane, char* ldsWaveBase) {
  #pragma unroll
  for (int i = 0; i < 4; ++i)
    __builtin_amdgcn_global_load_lds((const __attribute__((address_space(1))) void*)(srcLane + i * 4096),
                                     (__attribute__((address_space(3))) void*)(ldsWaveBase + i * 4096), 16, 0, 0);
}

// ---------------- small kernels ----------------

// pack codebook to plain bf16 in MFMA-fragment order, 64-code tiles, H only; gid 0 zeroes acc
__global__ __launch_bounds__(256) void k_packcb(const float* __restrict__ cb, u16* __restrict__ cbp,
                                                float* __restrict__ acc4) {
  const int gid = blockIdx.x * 256 + threadIdx.x;
  if (gid == 0) { acc4[0] = 0.0f; acc4[1] = 0.0f; acc4[2] = 0.0f; acc4[3] = 0.0f; }
  if (gid >= 32768) return;
  const int lane = gid & 63;
  const int f = (gid >> 6) & 15;
  const int T = gid >> 10;
  const int ks = f >> 2, nf = f & 3;
  const int hi = lane >> 4, l15 = lane & 15;
  const int c = T * 64 + nf * 16 + l15;
  const int d0 = ks * 32 + hi * 8;
  const float4 v0 = *(const float4*)(cb + (size_t)c * DIMD + d0);
  const float4 v1 = *(const float4*)(cb + (size_t)c * DIMD + d0 + 4);
  const float e[8] = {v0.x, v0.y, v0.z, v0.w, v1.x, v1.y, v1.z, v1.w};
  union { u16 s[8]; u16x8 u; } oh;
  #pragma unroll
  for (int i = 0; i < 8; ++i) oh.s[i] = f2bf(e[i]);
  u16* tile = cbp + (size_t)T * 8192;
  *(u16x8*)(tile + (f * 64 + lane) * 8) = oh.u;
}

// ---------------- sweep: bf16 MFMA over HALF the codebook per block; per-lane int top-2 ----------------
// grid = 1024: blockIdx = rowgrp*2 + half. 4 waves x 32 rows (m=2). 4 blocks/CU.

__global__ __launch_bounds__(256, 4) void k_sweep(const float* __restrict__ x, const float* __restrict__ mask,
                                                  const u16* __restrict__ cbp, int* __restrict__ kvBuf) {
  __shared__ __align__(16) char Bsmem[32768];  // 2 x 16KB tiles
  const int tid = threadIdx.x;
  const int lane = tid & 63, w = tid >> 6;     // 4 waves
  const int l15 = lane & 15, hi = lane >> 4;
  const int half = blockIdx.x & 1;
  const int row0 = (blockIdx.x >> 1) * 128;
  const char* src = (const char*)cbp + (size_t)half * 262144;  // 16 tiles x 16KB

  // fused prep: load x f32, row-norm via 2-step shuffle (4 lanes/row), to plain bf16 in regs
  U8 Ah[2][4];
  #pragma unroll
  for (int mf = 0; mf < 2; ++mf) {
    const int row = row0 + w * 32 + mf * 16 + l15;
    const float add = (1.0f - mask[row]) * 1e-6f;
    const float* xr = x + (size_t)row * DIMD + hi * 8;
    float xf[4][8];
    float ss = 0.f;
    #pragma unroll
    for (int ks = 0; ks < 4; ++ks) {
      const float4 a = *(const float4*)(xr + ks * 32);
      const float4 bq = *(const float4*)(xr + ks * 32 + 4);
      xf[ks][0] = a.x + add;  xf[ks][1] = a.y + add;  xf[ks][2] = a.z + add;  xf[ks][3] = a.w + add;
      xf[ks][4] = bq.x + add; xf[ks][5] = bq.y + add; xf[ks][6] = bq.z + add; xf[ks][7] = bq.w + add;
      #pragma unroll
      for (int e = 0; e < 8; ++e) ss = fmaf(xf[ks][e], xf[ks][e], ss);
    }
    ss += __shfl_xor(ss, 16, 64);
    ss += __shfl_xor(ss, 32, 64);
    const float sc = 1.0f / fmaxf(sqrtf(ss), 1e-6f);
    #pragma unroll
    for (int ks = 0; ks < 4; ++ks) {
      union { u16 s[8]; u16x8 u; } th;
      #pragma unroll
      for (int e = 0; e < 8; ++e) th.s[e] = f2bf(xf[ks][e] * sc);
      Ah[mf][ks].u = th.u;
    }
  }

  // index-packed top-2 keys: key = (asint(score) & ~2047) | code_index
  int kv1[8], kv2[8];
  #pragma unroll
  for (int r = 0; r < 8; ++r) { kv1[r] = 0x80000000; kv2[r] = 0x80000000; }

  stage4(src + 0 * 16384 + tid * 16, Bsmem + 0 * 16384 + w * 1024);

  for (int t = 0; t < 16; ++t) {
    const int b = t & 1;
    asm volatile("s_waitcnt vmcnt(0)" ::: "memory");
    __builtin_amdgcn_sched_barrier(0);
    __builtin_amdgcn_s_barrier();
    __builtin_amdgcn_sched_barrier(0);
    if (t < 15)
      stage4(src + (size_t)(t + 1) * 16384 + tid * 16, Bsmem + (b ^ 1) * 16384 + w * 1024);

    const char* base = Bsmem + b * 16384 + lane * 16;
    f32x4 acc[2][4];
    #pragma unroll
    for (int m = 0; m < 2; ++m)
      #pragma unroll
      for (int nf = 0; nf < 4; ++nf) acc[m][nf] = (f32x4){0.f, 0.f, 0.f, 0.f};

    __builtin_amdgcn_s_setprio(1);
    #pragma unroll
    for (int ks = 0; ks < 4; ++ks) {
      #pragma unroll
      for (int nf = 0; nf < 4; ++nf) {
        U8 bh;
        bh.u = *(const u16x8*)(base + ((ks * 4 + nf) << 10));
        acc[0][nf] = __builtin_amdgcn_mfma_f32_16x16x32_bf16(Ah[0][ks].b, bh.b, acc[0][nf], 0, 0, 0);
        acc[1][nf] = __builtin_amdgcn_mfma_f32_16x16x32_bf16(Ah[1][ks].b, bh.b, acc[1][nf], 0, 0, 0);
      }
    }
    __builtin_amdgcn_s_setprio(0);

    // epilogue: index-packed int top-2 (pure max/min tree; overlaps in-flight prefetch)
    const int base11 = half * 1024 + t * 64 + l15;
    #pragma unroll
    for (int m = 0; m < 2; ++m)
      #pragma unroll
      for (int rg = 0; rg < 4; ++rg) {
        const int r = m * 4 + rg;
        int kk[4];
        #pragma unroll
        for (int nf = 0; nf < 4; ++nf) {
          union { float f; int i; } cv;
          cv.f = acc[m][nf][rg];
          kk[nf] = (cv.i & 0xFFFFF800) | (base11 + nf * 16);
        }
        const int h1 = imax(kk[0], kk[1]), lo1 = imin(kk[0], kk[1]);
        const int h2 = imax(kk[2], kk[3]), lo2 = imin(kk[2], kk[3]);
        const int t1 = imax(h1, h2);
        const int t2 = imax(imin(h1, h2), (h1 > h2) ? lo1 : lo2);
        kv2[r] = imax(imax(kv2[r], t2), imin(kv1[r], t1));
        kv1[r] = imax(kv1[r], t1);
      }
  }

  // write per-lane top-2 keys: kvBuf[row*64 + half*32 + l15*2 + {0,1}]
  #pragma unroll
  for (int m = 0; m < 2; ++m)
    #pragma unroll
    for (int rg = 0; rg < 4; ++rg) {
      const int r = m * 4 + rg;
      const int row = row0 + w * 32 + m * 16 + hi * 4 + rg;
      int2 kv;
      kv.x = kv1[r];
      kv.y = kv2[r];
      *(int2*)(kvBuf + (size_t)row * 64 + half * 32 + l15 * 2) = kv;
    }
}

// ---------------- tail: merge 64 keys/row, exact refine, gather, histograms, stats ----------------
// 256 blocks x 16 waves (1024 threads); one wave per row per iteration -> 16 rows/wave.

__global__ __launch_bounds__(1024) void k_tail(const float* __restrict__ x, const float* __restrict__ mask,
                                               const float* __restrict__ cb, const int* __restrict__ kvBuf,
                                               float* __restrict__ outQ, float* __restrict__ outEnc,
                                               float* __restrict__ apPart, float* __restrict__ cnPart,
                                               float* __restrict__ acc4) {
  __shared__ float ap[KCB];
  __shared__ float cn[KCB];
  __shared__ float smr[48];
  const int tid = threadIdx.x;
  const int lane = tid & 63, w = tid >> 6;   // 16 waves
  for (int i = tid; i < KCB; i += 1024) { ap[i] = 0.0f; cn[i] = 0.0f; }
  __syncthreads();

  float msum = 0.f, slat = 0.f, sent = 0.f;
  for (int row = blockIdx.x * 16 + w; row < NTOK; row += TSLAB * 16) {
    const int key = kvBuf[(size_t)row * 64 + lane];
    // row max over the 64 keys (int compare == float compare for the positive max)
    int mx = key;
    #pragma unroll
    for (int off = 1; off <= 32; off <<= 1) {
      const int ok = __shfl_xor(mx, off, 64);
      mx = ok > mx ? ok : mx;
    }
    const float a1val = keyval(mx);
    const float myval = keyval(key);
    const float mkk = mask[row];
    const float add = (1.0f - mkk) * 1e-6f;
    // normalized x: 2 dims per lane
    const float2 xv = *(const float2*)(x + (size_t)row * DIMD + lane * 2);
    const float x0 = xv.x + add, x1 = xv.y + add;
    float ss = fmaf(x0, x0, x1 * x1);
    #pragma unroll
    for (int off = 1; off <= 32; off <<= 1) ss += __shfl_xor(ss, off, 64);
    const float sc = 1.0f / fmaxf(sqrtf(ss), 1e-6f);
    // exact re-score of all candidates within RT of the bf16 max
    unsigned long long cmask = __ballot(myval > a1val - 4e-3f);
    float bestd = -1e30f;
    int bestk = 0x7fffffff;
    while (cmask) {
      const int s = __builtin_ctzll(cmask);
      cmask &= cmask - 1;
      const int kc = __shfl(key, s, 64) & 2047;
      const float2 cv = *(const float2*)(cb + (size_t)kc * DIMD + lane * 2);
      float d = fmaf(x0, cv.x, x1 * cv.y);
      #pragma unroll
      for (int off = 1; off <= 32; off <<= 1) d += __shfl_xor(d, off, 64);
      if (d > bestd || (d == bestd && kc < bestk)) { bestd = d; bestk = kc; }
    }
    const float bestv = bestd * sc;
    // histogram weights over all 64 keys (loose-threshold outputs)
    float q = 0.f, qd = 0.f;
    if (myval > a1val - 0.055f) {
      const float d = 200.f * (myval - a1val);
      q = __expf(d);
      qd = q * d;
    }
    float Z = q, S = qd;
    #pragma unroll
    for (int off = 1; off <= 32; off <<= 1) {
      Z += __shfl_xor(Z, off, 64);
      S += __shfl_xor(S, off, 64);
    }
    if (q > 0.f) atomicAdd(&ap[key & 2047], mkk * q / Z);
    // gather the exact-argmax codebook row (2 floats per lane)
    const float2 g = *(const float2*)(cb + (size_t)bestk * DIMD + lane * 2);
    *(float2*)(outQ + (size_t)row * DIMD + lane * 2) = g;
    if (lane == 0) {
      atomicAdd(&cn[bestk], mkk);
      outEnc[row] = (float)bestk;
      msum += mkk;
      slat = fmaf(mkk, 2.0f - 2.0f * bestv, slat);
      sent = fmaf(mkk, __logf(Z) - S / Z, sent);
    }
  }
  // block-reduce the three scalars (only lane 0 holds nonzero)
  #pragma unroll
  for (int off = 1; off <= 32; off <<= 1) {
    msum += __shfl_xor(msum, off, 64);
    slat += __shfl_xor(slat, off, 64);
    sent += __shfl_xor(sent, off, 64);
  }
  if (lane == 0) { smr[w * 3] = msum; smr[w * 3 + 1] = slat; smr[w * 3 + 2] = sent; }
  __syncthreads();
  if (tid == 0) {
    float t0 = 0.f, t1 = 0.f, t2 = 0.f;
    #pragma unroll
    for (int v = 0; v < 16; ++v) { t0 += smr[v * 3]; t1 += smr[v * 3 + 1]; t2 += smr[v * 3 + 2]; }
    atomicAdd(&acc4[0], t0);
    atomicAdd(&acc4[1], t1);
    atomicAdd(&acc4[2], t2);
  }
  float* apDst = apPart + (size_t)blockIdx.x * KCB;
  float* cnDst = cnPart + (size_t)blockIdx.x * KCB;
  for (int i = tid; i < KCB; i += 1024) {
    apDst[i] = ap[i];
    cnDst[i] = cn[i];
  }
}

// reduce partial slabs -> avgp-entropy partials + outCnt. 64 blocks x 256 threads, coalesced.
__global__ __launch_bounds__(256) void k_reduce(const float* __restrict__ apPart, const float* __restrict__ cnPart,
                                                const float* __restrict__ acc4In, float* __restrict__ outCnt,
                                                float* __restrict__ acc4) {
  __shared__ float sa8[8][32];
  __shared__ float sc8[8][32];
  const int tid = threadIdx.x;
  const int kloc = tid & 31, sg = tid >> 5;
  const int k = blockIdx.x * 32 + kloc;
  float sa = 0.f, sc = 0.f;
  #pragma unroll
  for (int i = 0; i < 32; ++i) {
    const int s = sg * 32 + i;
    sa += apPart[(size_t)s * KCB + k];
    sc += cnPart[(size_t)s * KCB + k];
  }
  sa8[sg][kloc] = sa;
  sc8[sg][kloc] = sc;
  __syncthreads();
  if (tid < 32) {
    float ta = 0.f, tc = 0.f;
    #pragma unroll
    for (int g = 0; g < 8; ++g) { ta += sa8[g][tid]; tc += sc8[g][tid]; }
    outCnt[blockIdx.x * 32 + tid] = tc;
    const float a = ta / acc4In[0];
    float ae = a * __logf(a + 1e-5f);
    #pragma unroll
    for (int off = 1; off <= 16; off <<= 1) ae += __shfl_xor(ae, off, 64);
    if (tid == 0) atomicAdd(&acc4[3], ae);
  }
}

__global__ __launch_bounds__(64) void k_final(const float* __restrict__ acc4, float* __restrict__ out3) {
  if (threadIdx.x == 0) {
    const float msum = acc4[0];
    const float lat = acc4[1] / (msum + 1e-6f);
    out3[0] = lat;
    out3[1] = lat;
    out3[2] = acc4[2] / msum + acc4[3];  // sample_entropy - avg_entropy
  }
}

// ---------------- launcher ----------------

extern "C" void kernel_launch(void* const* d_in, const int* in_sizes, int n_in,
                              void* d_out, int out_size, void* d_ws, size_t ws_size,
                              hipStream_t stream) {
  const float* x = (const float*)d_in[0];
  const float* mask = (const float*)d_in[1];
  const float* cb = (const float*)d_in[2];

  float* out = (float*)d_out;
  float* outQ = out;
  float* out3 = out + (size_t)NTOK * DIMD;
  float* outCnt = out3 + 3;
  float* outEnc = outCnt + KCB;

  float* ws = (float*)d_ws;
  float* acc4 = ws;                                       // 4
  u16* cbp = (u16*)(acc4 + 8);                            // K*D u16 (512 KB, H only)
  int* kvBuf = (int*)(cbp + (size_t)KCB * DIMD);          // N*64 ints (16 MB)
  float* apPart = (float*)(kvBuf + (size_t)NTOK * 64);    // TSLAB*K (2 MB)
  float* cnPart = apPart + (size_t)TSLAB * KCB;           // TSLAB*K (2 MB)

  k_packcb<<<32768 / 256, 256, 0, stream>>>(cb, cbp, acc4);
  k_sweep<<<(NTOK / 128) * 2, 256, 0, stream>>>(x, mask, cbp, kvBuf);
  k_tail<<<TSLAB, 1024, 0, stream>>>(x, mask, cb, kvBuf, outQ, outEnc, apPart, cnPart, acc4);
  k_reduce<<<64, 256, 0, stream>>>(apPart, cnPart, acc4, outCnt, acc4);
  k_final<<<1, 64, 0, stream>>>(acc4, out3);
}